// Round 8
// baseline (239.786 us; speedup 1.0000x reference)
//
#include <hip/hip_runtime.h>
#include <cfloat>

#define N_PTS 8192
#define DTOK 256
#define KNN 16

typedef __attribute__((ext_vector_type(8))) short short8;
typedef __attribute__((ext_vector_type(4))) float float4v;
typedef __attribute__((ext_vector_type(2))) float float2v;

__device__ inline short f2bf(float f) {   // RTNE fp32 -> bf16
  unsigned u = __float_as_uint(f);
  u += 0x7fffu + ((u >> 16) & 1u);
  return (short)(u >> 16);
}
__device__ inline float bf2f(short h) {
  return __uint_as_float(((unsigned)(unsigned short)h) << 16);
}

// ---- VOP3P packed fp32 helpers: 2 IEEE-RN fp32 ops per issue slot --------
__device__ inline float2v pk_mul(float2v a, float2v b) {
  float2v d;
  asm("v_pk_mul_f32 %0, %1, %2" : "=v"(d) : "v"(a), "v"(b));
  return d;
}
__device__ inline float2v pk_fma(float2v a, float2v b, float2v c) {
  float2v d;
  asm("v_pk_fma_f32 %0, %1, %2, %3" : "=v"(d) : "v"(a), "v"(b), "v"(c));
  return d;
}
__device__ inline float2v pk_add(float2v a, float2v b) {
  float2v d;
  asm("v_pk_add_f32 %0, %1, %2" : "=v"(d) : "v"(a), "v"(b));
  return d;
}

// ---------------------------------------------------------------------------
// Pack xyz -> (x,y,z,sq) with the exact rounding the old knn used, so all
// distances (and thus KNN indices) are bit-identical.
// ---------------------------------------------------------------------------
__global__ __launch_bounds__(256) void knn_prep_kernel(
    const float* __restrict__ xyz, float4* __restrict__ xyz4) {
  const int i = blockIdx.x * 256 + threadIdx.x;
  float x = xyz[3 * i], y = xyz[3 * i + 1], z = xyz[3 * i + 2];
  float sq = __fadd_rn(__fadd_rn(__fmul_rn(x, x), __fmul_rn(y, y)),
                       __fmul_rn(z, z));
  xyz4[i] = make_float4(x, y, z, sq);
}

// Serial stable top-16 insert for one 64-candidate group (unchanged from v5).
__device__ inline void insert_group(float d, int base, float t, int lane,
                                    float& sd, int& sj, float& s15) {
  unsigned long long m = __ballot(d <= t);
  while (m) {                          // m is wave-uniform
    const int src = __ffsll(m) - 1;    // ascending lane == ascending j
    m &= m - 1;
    const float dc = __shfl(d, src);
    if (dc < s15) {                    // recheck vs running bound
      const int jc = base + src;
      const unsigned long long bm = __ballot(sd <= dc) & 0xFFFFull;
      const int pos = (int)__popcll(bm);      // stable position
      const float pu = __shfl_up(sd, 1);
      const int ju = __shfl_up(sj, 1);
      if (lane < 16) {
        if (lane > pos)        { sd = pu; sj = ju; }
        else if (lane == pos)  { sd = dc; sj = jc; }
      }
      s15 = __shfl(sd, 15);
    }
  }
}

// ---------------------------------------------------------------------------
// W1 -> Bt (transposed, n-major) bf16 hi/lo (frozen).
// ---------------------------------------------------------------------------
__global__ __launch_bounds__(256) void convert_w_kernel(
    const float* __restrict__ W1, short* __restrict__ bhi,
    short* __restrict__ blo) {
  const int n = blockIdx.x;      // 0..511
  const int k = threadIdx.x;     // 0..255
  const float v = (n < 256) ? W1[k * DTOK + n]
                            : W1[(259 + k) * DTOK + (n - 256)];
  short h = f2bf(v);
  bhi[n * 256 + k] = h;
  blo[n * 256 + k] = f2bf(v - bf2f(h));
}

// ---------------------------------------------------------------------------
// FUSED knn_select (v11) + pq_gemm (layer a): horizontal grid fusion.
// R7 post-mortem: no single kernel dominates anymore; the serial launch
// chain has ~30us of hideable independent work (knn !-> gemm_a). Fusion:
// 1536 blocks, bid%3==2 -> gemm tile (512 = old dim3(128,4) linearized),
// else -> knn block (1024, v11 code verbatim). LDS arena 27136B so that
// 6 blocks/CU x 256 CU = all 1536 co-resident (24 waves/CU): gemm's Qs
// (16.6KB) is ALIASED over the dead-after-K-loop A/B tiles (24.5KB) with
// one added __syncthreads() between last MFMA-read and first Qs write.
// knn path: VALU/LDS/VMEM, no MFMA; gemm path: MFMA-heavy -> m114-style
// pipe overlap. Both paths byte-identical math to the proven kernels ->
// outputs bit-identical. Layer b keeps the standalone gemm kernel.
// ---------------------------------------------------------------------------
#define KCH 512                     // candidates per staged chunk (pass A)
#define NCH (N_PTS / KCH)           // 16 chunks

__global__ __launch_bounds__(256, 2) void knn_gemm_fused_kernel(
    const float4* __restrict__ xyz4, int* __restrict__ nbr,
    const float* __restrict__ A, const short* __restrict__ Bthi,
    const short* __restrict__ Btlo, const float* __restrict__ xyz,
    const float* __restrict__ W1, const float* __restrict__ b1,
    float* __restrict__ R, float* __restrict__ Q) {
  __shared__ __align__(16) char smem[27136];

  const int bid = blockIdx.x;
  const int tid = threadIdx.x;
  const int lane = tid & 63;
  const int wave = tid >> 6;
  const int l15 = lane & 15;
  const int quad = lane >> 4;

  if (bid % 3 != 2) {
    // =================== KNN path (v11, verbatim) ===================
    float4 (*sA)[4][64] = (float4 (*)[4][64])(smem);          // 8 KB
    float4 (*sB)[4][64] = (float4 (*)[4][64])(smem + 8192);   // 8 KB

    const int kb = (bid / 3) * 2 + (bid % 3);   // knn block 0..1023
    const int i0 = kb * 8 + wave * 2;
    const int i1 = i0 + 1;

    const float4 q0 = xyz4[i0];
    const float4 q1 = xyz4[i1];
    const float2v x02 = {q0.x, q0.x}, y02 = {q0.y, q0.y};
    const float2v z02 = {q0.z, q0.z}, s02 = {q0.w, q0.w};
    const float2v x12 = {q1.x, q1.x}, y12 = {q1.y, q1.y};
    const float2v z12 = {q1.z, q1.z}, s12 = {q1.w, q1.w};
    const float2v n2 = {-2.0f, -2.0f};

    const int ib128 = i0 & ~127;
    const int ih0 = (i0 >> 6) & 1, il0 = i0 & 63;
    const int ih1 = (i1 >> 6) & 1, il1 = i1 & 63;

    const int sgj = wave * 128 + lane;

    {
      const float4 c0 = xyz4[sgj];
      const float4 c1 = xyz4[sgj + 64];
      sA[0][wave][lane] = make_float4(c0.x, c1.x, c0.y, c1.y);
      sB[0][wave][lane] = make_float4(c0.z, c1.z, c0.w, c1.w);
    }
    __syncthreads();

    float a00 = FLT_MAX, a01 = FLT_MAX, a10 = FLT_MAX, a11 = FLT_MAX;
    for (int c = 0; c < NCH; ++c) {
      const int b = c & 1;
      float4 nx0, nx1;
      if (c < NCH - 1) {              // issue next-chunk loads early (T14)
        nx0 = xyz4[(c + 1) * KCH + sgj];
        nx1 = xyz4[(c + 1) * KCH + sgj + 64];
      }
      const int cbase = c * KCH;
      #pragma unroll
      for (int ps = 0; ps < 4; ++ps) {
        const float4 a = sA[b][ps][lane];
        const float4 bb = sB[b][ps][lane];
        const float2v px = {a.x, a.y}, py = {a.z, a.w};
        const float2v pz = {bb.x, bb.y}, pw = {bb.z, bb.w};
        const bool selfg = (cbase + ps * 128 == ib128);   // uniform
        const float2v dot0 =
            pk_fma(z02, pz, pk_fma(y02, py, pk_mul(x02, px)));
        float2v d0 = pk_add(pk_fma(n2, dot0, s02), pw);
        const float2v dot1 =
            pk_fma(z12, pz, pk_fma(y12, py, pk_mul(x12, px)));
        float2v d1 = pk_add(pk_fma(n2, dot1, s12), pw);
        if (selfg) {                        // uniform rare branch
          if (lane == il0) {
            if (ih0) d0.y = __fadd_rn(d0.y, 1e10f);
            else     d0.x = __fadd_rn(d0.x, 1e10f);
          }
          if (lane == il1) {
            if (ih1) d1.y = __fadd_rn(d1.y, 1e10f);
            else     d1.x = __fadd_rn(d1.x, 1e10f);
          }
        }
        a00 = fminf(a00, d0.x);
        a01 = fminf(a01, d0.y);
        a10 = fminf(a10, d1.x);
        a11 = fminf(a11, d1.y);
      }
      if (c < NCH - 1) {              // LDS write late; latency hidden
        sA[b ^ 1][wave][lane] = make_float4(nx0.x, nx1.x, nx0.y, nx1.y);
        sB[b ^ 1][wave][lane] = make_float4(nx0.z, nx1.z, nx0.w, nx1.w);
      }
      __syncthreads();
    }

    float v0 = fminf(a00, a01);
    float v1 = fminf(a10, a11);
    #pragma unroll
    for (int k = 2; k <= 64; k <<= 1) {
      #pragma unroll
      for (int j = k >> 1; j > 0; j >>= 1) {
        const float o0 = __shfl_xor(v0, j, 64);
        const float o1 = __shfl_xor(v1, j, 64);
        const bool keepmin = ((lane & k) == 0) == ((lane & j) == 0);
        v0 = keepmin ? fminf(v0, o0) : fmaxf(v0, o0);
        v1 = keepmin ? fminf(v1, o1) : fmaxf(v1, o1);
      }
    }
    const float t0 = __shfl(v0, 15, 64);
    const float t1 = __shfl(v1, 15, 64);

    // pass B: stream directly from global (L2-resident), no barriers
    float sd0 = FLT_MAX, sd1 = FLT_MAX;
    int sj0 = 0, sj1 = 0;
    float s150 = FLT_MAX, s151 = FLT_MAX;

    const int gself = i0 >> 6;

    float4 pc = xyz4[lane];
    #pragma unroll 2
    for (int grp = 0; grp < N_PTS / 64; ++grp) {
      float4 pn;
      if (grp < N_PTS / 64 - 1) pn = xyz4[(grp + 1) * 64 + lane];

      const float dot0 = fmaf(q0.z, pc.z, fmaf(q0.y, pc.y,
                                               __fmul_rn(q0.x, pc.x)));
      float d0 = __fadd_rn(__fmaf_rn(-2.0f, dot0, q0.w), pc.w);
      const float dot1 = fmaf(q1.z, pc.z, fmaf(q1.y, pc.y,
                                               __fmul_rn(q1.x, pc.x)));
      float d1 = __fadd_rn(__fmaf_rn(-2.0f, dot1, q1.w), pc.w);
      if (grp == gself) {                 // uniform rare branch
        if (lane == il0) d0 = __fadd_rn(d0, 1e10f);
        if (lane == il1) d1 = __fadd_rn(d1, 1e10f);
      }

      insert_group(d0, grp * 64, t0, lane, sd0, sj0, s150);
      insert_group(d1, grp * 64, t1, lane, sd1, sj1, s151);
      pc = pn;
    }

    if (lane < 16) {
      nbr[i0 * KNN + lane] = sj0;
      nbr[i1 * KNN + lane] = sj1;
    }
    return;
  }

  // =================== GEMM path (pq_gemm v2, LDS-aliased) ===================
  short (*Ahi)[32] = (short (*)[32])(smem);            // 4 KB
  short (*Alo)[32] = (short (*)[32])(smem + 4096);     // 4 KB
  short (*Bhi)[32] = (short (*)[32])(smem + 8192);     // 8 KB
  short (*Blo)[32] = (short (*)[32])(smem + 16384);    // 8 KB
  float (*Qs)[65]  = (float (*)[65])(smem);            // 16.6 KB ALIAS of A/B
  float (*sx)[3]   = (float (*)[3])(smem + 24576);     // 768 B
  float (*swz)[64] = (float (*)[64])(smem + 25344);    // 1.5 KB
  float* sb1       = (float*)(smem + 26880);           // 256 B

  const int g = bid / 3;               // 0..511
  const int m0 = (g >> 2) * 64;
  const int np0 = (g & 3) * 64;
  const int mh = wave & 1;
  const int qh = wave >> 1;

  if (tid < 64) {
    sx[tid][0] = xyz[(m0 + tid) * 3];
    sx[tid][1] = xyz[(m0 + tid) * 3 + 1];
    sx[tid][2] = xyz[(m0 + tid) * 3 + 2];
  } else if (tid < 128) {
    int n = tid - 64;
    sb1[n] = b1[np0 + n];
    #pragma unroll
    for (int r = 0; r < 3; ++r) {
      swz[r][n] = W1[(256 + r) * DTOK + np0 + n];
      swz[3 + r][n] = W1[(515 + r) * DTOK + np0 + n];
    }
  }

  float4v acc[2][4];
  #pragma unroll
  for (int mf = 0; mf < 2; ++mf)
    #pragma unroll
    for (int nf = 0; nf < 4; ++nf)
      #pragma unroll
      for (int e = 0; e < 4; ++e) acc[mf][nf][e] = 0.f;

  const int ar = tid >> 2;             // A staging row 0..63
  const int ak = (tid & 3) * 8;        // A staging k-offset

  #pragma unroll 1
  for (int kc = 0; kc < 8; ++kc) {
    const int k0 = kc * 32;
    __syncthreads();
    {
      const float* asrc = A + (size_t)(m0 + ar) * 256 + k0 + ak;
      float4 a0 = *(const float4*)asrc;
      float4 a1 = *(const float4*)(asrc + 4);
      float v[8] = {a0.x, a0.y, a0.z, a0.w, a1.x, a1.y, a1.z, a1.w};
      short8 h8, l8;
      #pragma unroll
      for (int e = 0; e < 8; ++e) {
        short h = f2bf(v[e]);
        h8[e] = h;
        l8[e] = f2bf(v[e] - bf2f(h));
      }
      *(short8*)(&Ahi[ar][ak]) = h8;
      *(short8*)(&Alo[ar][ak]) = l8;
    }
    #pragma unroll
    for (int l = 0; l < 4; ++l) {
      const int rem = tid + 256 * (l & 1);
      const int row = rem >> 2;
      const int koff = (rem & 3) * 8;
      const int n = (row < 64) ? (np0 + row) : (256 + np0 + row - 64);
      const short* src = ((l < 2) ? Bthi : Btlo) + (size_t)n * 256 + k0 + koff;
      short8 vv = *(const short8*)src;
      if (l < 2) *(short8*)(&Bhi[row][koff]) = vv;
      else       *(short8*)(&Blo[row][koff]) = vv;
    }
    __syncthreads();

    short8 ah[2], al[2], bh[4], bl[4];
    #pragma unroll
    for (int mf = 0; mf < 2; ++mf) {
      ah[mf] = *(const short8*)(&Ahi[mh * 32 + mf * 16 + l15][quad * 8]);
      al[mf] = *(const short8*)(&Alo[mh * 32 + mf * 16 + l15][quad * 8]);
    }
    #pragma unroll
    for (int nf = 0; nf < 4; ++nf) {
      bh[nf] = *(const short8*)(&Bhi[qh * 64 + nf * 16 + l15][quad * 8]);
      bl[nf] = *(const short8*)(&Blo[qh * 64 + nf * 16 + l15][quad * 8]);
    }
    #pragma unroll
    for (int mf = 0; mf < 2; ++mf)
      #pragma unroll
      for (int nf = 0; nf < 4; ++nf) {
        acc[mf][nf] = __builtin_amdgcn_mfma_f32_16x16x32_bf16(
            ah[mf], bh[nf], acc[mf][nf], 0, 0, 0);
        acc[mf][nf] = __builtin_amdgcn_mfma_f32_16x16x32_bf16(
            ah[mf], bl[nf], acc[mf][nf], 0, 0, 0);
        acc[mf][nf] = __builtin_amdgcn_mfma_f32_16x16x32_bf16(
            al[mf], bh[nf], acc[mf][nf], 0, 0, 0);
      }
  }

  // NEW barrier: A/B tiles are dead past here; Qs aliases them.
  __syncthreads();

  if (qh == 1) {
    #pragma unroll
    for (int mf = 0; mf < 2; ++mf)
      #pragma unroll
      for (int nf = 0; nf < 4; ++nf)
        #pragma unroll
        for (int e = 0; e < 4; ++e) {
          int row = mh * 32 + mf * 16 + quad * 4 + e;
          int col = nf * 16 + l15;
          float q = acc[mf][nf][e] + sx[row][0] * swz[3][col] +
                    sx[row][1] * swz[4][col] + sx[row][2] * swz[5][col];
          Qs[row][col] = q;
          Q[(size_t)(m0 + row) * DTOK + np0 + col] = q;
        }
  }
  __syncthreads();
  if (qh == 0) {
    #pragma unroll
    for (int mf = 0; mf < 2; ++mf)
      #pragma unroll
      for (int nf = 0; nf < 4; ++nf)
        #pragma unroll
        for (int e = 0; e < 4; ++e) {
          int row = mh * 32 + mf * 16 + quad * 4 + e;
          int col = nf * 16 + l15;
          float p = acc[mf][nf][e] + sx[row][0] * swz[0][col] +
                    sx[row][1] * swz[1][col] + sx[row][2] * swz[2][col];
          R[(size_t)(m0 + row) * DTOK + np0 + col] =
              (p + sb1[col]) - Qs[row][col];
        }
  }
}

// ---------------------------------------------------------------------------
// pq GEMM v2 (frozen from R9) -- standalone, used for layer b.
// ---------------------------------------------------------------------------
__global__ __launch_bounds__(256, 2) void pq_gemm_fused_kernel(
    const float* __restrict__ A, const short* __restrict__ Bthi,
    const short* __restrict__ Btlo, const float* __restrict__ xyz,
    const float* __restrict__ W1, const float* __restrict__ b1,
    float* __restrict__ R, float* __restrict__ Q) {
  __shared__ short Ahi[64][32], Alo[64][32];    // 4K + 4K
  __shared__ short Bhi[128][32], Blo[128][32];  // 8K + 8K
  __shared__ float Qs[64][65];                  // 16.6K
  __shared__ float sx[64][3];
  __shared__ float swz[6][64];
  __shared__ float sb1[64];

  const int tid = threadIdx.x;
  const int lane = tid & 63;
  const int wave = tid >> 6;
  const int l15 = lane & 15;
  const int quad = lane >> 4;
  const int mh = wave & 1;
  const int qh = wave >> 1;
  const int m0 = blockIdx.x * 64;
  const int np0 = blockIdx.y * 64;

  if (tid < 64) {
    sx[tid][0] = xyz[(m0 + tid) * 3];
    sx[tid][1] = xyz[(m0 + tid) * 3 + 1];
    sx[tid][2] = xyz[(m0 + tid) * 3 + 2];
  } else if (tid < 128) {
    int n = tid - 64;
    sb1[n] = b1[np0 + n];
    #pragma unroll
    for (int r = 0; r < 3; ++r) {
      swz[r][n] = W1[(256 + r) * DTOK + np0 + n];
      swz[3 + r][n] = W1[(515 + r) * DTOK + np0 + n];
    }
  }

  float4v acc[2][4];
  #pragma unroll
  for (int mf = 0; mf < 2; ++mf)
    #pragma unroll
    for (int nf = 0; nf < 4; ++nf)
      #pragma unroll
      for (int e = 0; e < 4; ++e) acc[mf][nf][e] = 0.f;

  const int ar = tid >> 2;             // A staging row 0..63
  const int ak = (tid & 3) * 8;        // A staging k-offset

  #pragma unroll 1
  for (int kc = 0; kc < 8; ++kc) {
    const int k0 = kc * 32;
    __syncthreads();
    {
      const float* asrc = A + (size_t)(m0 + ar) * 256 + k0 + ak;
      float4 a0 = *(const float4*)asrc;
      float4 a1 = *(const float4*)(asrc + 4);
      float v[8] = {a0.x, a0.y, a0.z, a0.w, a1.x, a1.y, a1.z, a1.w};
      short8 h8, l8;
      #pragma unroll
      for (int e = 0; e < 8; ++e) {
        short h = f2bf(v[e]);
        h8[e] = h;
        l8[e] = f2bf(v[e] - bf2f(h));
      }
      *(short8*)(&Ahi[ar][ak]) = h8;
      *(short8*)(&Alo[ar][ak]) = l8;
    }
    #pragma unroll
    for (int l = 0; l < 4; ++l) {
      const int rem = tid + 256 * (l & 1);
      const int row = rem >> 2;
      const int koff = (rem & 3) * 8;
      const int n = (row < 64) ? (np0 + row) : (256 + np0 + row - 64);
      const short* src = ((l < 2) ? Bthi : Btlo) + (size_t)n * 256 + k0 + koff;
      short8 vv = *(const short8*)src;
      if (l < 2) *(short8*)(&Bhi[row][koff]) = vv;
      else       *(short8*)(&Blo[row][koff]) = vv;
    }
    __syncthreads();

    short8 ah[2], al[2], bh[4], bl[4];
    #pragma unroll
    for (int mf = 0; mf < 2; ++mf) {
      ah[mf] = *(const short8*)(&Ahi[mh * 32 + mf * 16 + l15][quad * 8]);
      al[mf] = *(const short8*)(&Alo[mh * 32 + mf * 16 + l15][quad * 8]);
    }
    #pragma unroll
    for (int nf = 0; nf < 4; ++nf) {
      bh[nf] = *(const short8*)(&Bhi[qh * 64 + nf * 16 + l15][quad * 8]);
      bl[nf] = *(const short8*)(&Blo[qh * 64 + nf * 16 + l15][quad * 8]);
    }
    #pragma unroll
    for (int mf = 0; mf < 2; ++mf)
      #pragma unroll
      for (int nf = 0; nf < 4; ++nf) {
        acc[mf][nf] = __builtin_amdgcn_mfma_f32_16x16x32_bf16(
            ah[mf], bh[nf], acc[mf][nf], 0, 0, 0);
        acc[mf][nf] = __builtin_amdgcn_mfma_f32_16x16x32_bf16(
            ah[mf], bl[nf], acc[mf][nf], 0, 0, 0);
        acc[mf][nf] = __builtin_amdgcn_mfma_f32_16x16x32_bf16(
            al[mf], bh[nf], acc[mf][nf], 0, 0, 0);
      }
  }

  if (qh == 1) {
    #pragma unroll
    for (int mf = 0; mf < 2; ++mf)
      #pragma unroll
      for (int nf = 0; nf < 4; ++nf)
        #pragma unroll
        for (int e = 0; e < 4; ++e) {
          int row = mh * 32 + mf * 16 + quad * 4 + e;
          int col = nf * 16 + l15;
          float q = acc[mf][nf][e] + sx[row][0] * swz[3][col] +
                    sx[row][1] * swz[4][col] + sx[row][2] * swz[5][col];
          Qs[row][col] = q;
          Q[(size_t)(m0 + row) * DTOK + np0 + col] = q;
        }
  }
  __syncthreads();
  if (qh == 0) {
    #pragma unroll
    for (int mf = 0; mf < 2; ++mf)
      #pragma unroll
      for (int nf = 0; nf < 4; ++nf)
        #pragma unroll
        for (int e = 0; e < 4; ++e) {
          int row = mh * 32 + mf * 16 + quad * 4 + e;
          int col = nf * 16 + l15;
          float p = acc[mf][nf][e] + sx[row][0] * swz[0][col] +
                    sx[row][1] * swz[1][col] + sx[row][2] * swz[2][col];
          R[(size_t)(m0 + row) * DTOK + np0 + col] =
              (p + sb1[col]) - Qs[row][col];
        }
  }
}

// ---------------------------------------------------------------------------
// EdgeConv via MFMA (EXACT R10 version -- R11's global-B variant regressed
// 68 -> ~110 us/launch; W2 register fragments restored).
// ---------------------------------------------------------------------------
#define EP 8          // points per group

__global__ __launch_bounds__(256, 2) void edge_mfma_kernel(
    const float* __restrict__ R, const float* __restrict__ Q,
    const int* __restrict__ nbr, const float* __restrict__ W2,
    const float* __restrict__ b2, float* __restrict__ out,
    int num_groups, int groups_per_block) {
  __shared__ short Hs[EP * KNN * DTOK];   // 128 rows x 256, 64 KB
  const int lane = threadIdx.x & 63;
  const int wave = threadIdx.x >> 6;
  const int l15 = lane & 15;
  const int quad = lane >> 4;

  short8 bfr[4][8];
  #pragma unroll
  for (int nt_i = 0; nt_i < 4; ++nt_i) {
    const int n = (wave * 4 + nt_i) * 16 + l15;
    #pragma unroll
    for (int kt = 0; kt < 8; ++kt) {
      short8 f;
      #pragma unroll
      for (int jj = 0; jj < 8; ++jj) {
        int k = kt * 32 + quad * 8 + jj;
        f[jj] = f2bf(W2[k * DTOK + n]);
      }
      bfr[nt_i][kt] = f;
    }
  }

  const int wc8 = lane >> 1;
  const int wsub = (lane & 1) * 4;

  for (int gi = 0; gi < groups_per_block; ++gi) {
    const int g = blockIdx.x + gi * gridDim.x;
    if (g >= num_groups) break;
    const int i0 = g * EP;

    // ---- build H: prefetched nbr via lane reg + shfl, pipelined gathers ----
    {
      const int ia = i0 + wave * 2;
      const int jr0 = nbr[ia * KNN + l15];
      const int jr1 = nbr[(ia + 1) * KNN + l15];
      const float4 ri0 = ((const float4*)(R + (size_t)ia * DTOK))[lane];
      const float4 ri1 = ((const float4*)(R + (size_t)(ia + 1) * DTOK))[lane];
      #pragma unroll
      for (int pp = 0; pp < 2; ++pp) {
        const float4 ri = pp ? ri1 : ri0;
        const int jr = pp ? jr1 : jr0;
        #pragma unroll
        for (int k = 0; k < KNN; ++k) {
          const int j = __shfl(jr, k, 16);
          const float4 qj = ((const float4*)(Q + (size_t)j * DTOK))[lane];
          const int r = wave * 32 + pp * 16 + k;
          uint2 pk;
          pk.x = ((unsigned)(unsigned short)f2bf(fmaxf(ri.x + qj.x, 0.f))) |
                 (((unsigned)(unsigned short)f2bf(fmaxf(ri.y + qj.y, 0.f))) << 16);
          pk.y = ((unsigned)(unsigned short)f2bf(fmaxf(ri.z + qj.z, 0.f))) |
                 (((unsigned)(unsigned short)f2bf(fmaxf(ri.w + qj.w, 0.f))) << 16);
          *(uint2*)(&Hs[r * DTOK + ((wc8 ^ (r & 7)) << 3) + wsub]) = pk;
        }
      }
    }
    __syncthreads();

    #pragma unroll
    for (int mp = 0; mp < 4; ++mp) {
      float4v acc[2][4];
      #pragma unroll
      for (int mi = 0; mi < 2; ++mi)
        #pragma unroll
        for (int nt_i = 0; nt_i < 4; ++nt_i)
          #pragma unroll
          for (int e = 0; e < 4; ++e) acc[mi][nt_i][e] = 0.f;

      #pragma unroll
      for (int kt = 0; kt < 8; ++kt) {
        const int pc = ((kt * 4 + quad) ^ (l15 & 7)) << 3;
        const short8 a0 = *(const short8*)(
            &Hs[((mp * 2 + 0) * 16 + l15) * DTOK + pc]);
        const short8 a1 = *(const short8*)(
            &Hs[((mp * 2 + 1) * 16 + l15) * DTOK + pc]);
        #pragma unroll
        for (int nt_i = 0; nt_i < 4; ++nt_i) {
          acc[0][nt_i] = __builtin_amdgcn_mfma_f32_16x16x32_bf16(
              a0, bfr[nt_i][kt], acc[0][nt_i], 0, 0, 0);
          acc[1][nt_i] = __builtin_amdgcn_mfma_f32_16x16x32_bf16(
              a1, bfr[nt_i][kt], acc[1][nt_i], 0, 0, 0);
        }
      }

      #pragma unroll
      for (int mi = 0; mi < 2; ++mi) {
        #pragma unroll
        for (int nt_i = 0; nt_i < 4; ++nt_i) {
          float rm = fmaxf(fmaxf(acc[mi][nt_i][0], acc[mi][nt_i][1]),
                           fmaxf(acc[mi][nt_i][2], acc[mi][nt_i][3]));
          rm = fmaxf(rm, __shfl_xor(rm, 16, 64));
          rm = fmaxf(rm, __shfl_xor(rm, 32, 64));
          if (lane < 16) {
            const int i = i0 + mp * 2 + mi;
            const int n = (wave * 4 + nt_i) * 16 + lane;
            out[(size_t)i * DTOK + n] = rm + b2[n];
          }
        }
      }
    }
    __syncthreads();
  }
}

// ---------------------------------------------------------------------------
extern "C" void kernel_launch(void* const* d_in, const int* in_sizes, int n_in,
                              void* d_out, int out_size, void* d_ws,
                              size_t ws_size, hipStream_t stream) {
  const float* xyz = (const float*)d_in[0];
  const float* feat = (const float*)d_in[1];
  const float* W1a = (const float*)d_in[2];
  const float* b1a = (const float*)d_in[3];
  const float* W2a = (const float*)d_in[4];
  const float* b2a = (const float*)d_in[5];
  const float* W1b = (const float*)d_in[6];
  const float* b1b = (const float*)d_in[7];
  const float* W2b = (const float*)d_in[8];
  const float* b2b = (const float*)d_in[9];
  float* out = (float*)d_out;

  // ws layout (~25 MB): nbr 0.5 | xyz4 128KB (then R at +8MB) | Q | Bt hi/lo
  char* w = (char*)d_ws;
  const size_t SZ_NBR = (size_t)N_PTS * KNN * sizeof(int);        // 512 KB
  const size_t MB = 1024 * 1024;
  int* nbr = (int*)w;
  char* w1 = w + SZ_NBR;
  float4* xyz4 = (float4*)w1;                  // 128 KB
  float* R = (float*)(w1 + 8 * MB);            // 8 MB
  float* Q = (float*)(w + SZ_NBR + 16 * MB);   // 8 MB
  short* Bthi = (short*)(w + SZ_NBR + 24 * MB);// 256 KB
  short* Btlo = Bthi + 512 * 256;              // 256 KB
  float* bufC = out;                           // layer-a output staging

  knn_prep_kernel<<<N_PTS / 256, 256, 0, stream>>>(xyz, xyz4);

  const int num_groups = N_PTS / EP;           // 1024
  const int nblocks = 512;

  // layer a: knn_select fused with pq_gemm_a (independent work, disjoint
  // pipes; all 1536 blocks co-resident at 6 blocks/CU)
  convert_w_kernel<<<512, 256, 0, stream>>>(W1a, Bthi, Btlo);
  knn_gemm_fused_kernel<<<1536, 256, 0, stream>>>(
      xyz4, nbr, feat, Bthi, Btlo, xyz, W1a, b1a, R, Q);
  edge_mfma_kernel<<<nblocks, 256, 0, stream>>>(R, Q, nbr, W2a, b2a, bufC,
                                                num_groups, 2);

  // layer b
  convert_w_kernel<<<512, 256, 0, stream>>>(W1b, Bthi, Btlo);
  pq_gemm_fused_kernel<<<dim3(N_PTS / 64, 4), 256, 0, stream>>>(
      bufC, Bthi, Btlo, xyz, W1b, b1b, R, Q);
  edge_mfma_kernel<<<nblocks, 256, 0, stream>>>(R, Q, nbr, W2b, b2b, out,
                                                num_groups, 2);
}

// Round 9
// 227.988 us; speedup vs baseline: 1.0517x; 1.0517x over previous
//
#include <hip/hip_runtime.h>
#include <cfloat>

#define N_PTS 8192
#define DTOK 256
#define KNN 16

typedef __attribute__((ext_vector_type(8))) short short8;
typedef __attribute__((ext_vector_type(4))) float float4v;
typedef __attribute__((ext_vector_type(2))) float float2v;

__device__ inline short f2bf(float f) {   // RTNE fp32 -> bf16
  unsigned u = __float_as_uint(f);
  u += 0x7fffu + ((u >> 16) & 1u);
  return (short)(u >> 16);
}
__device__ inline float bf2f(short h) {
  return __uint_as_float(((unsigned)(unsigned short)h) << 16);
}

// ---- VOP3P packed fp32 helpers: 2 IEEE-RN fp32 ops per issue slot --------
__device__ inline float2v pk_mul(float2v a, float2v b) {
  float2v d;
  asm("v_pk_mul_f32 %0, %1, %2" : "=v"(d) : "v"(a), "v"(b));
  return d;
}
__device__ inline float2v pk_fma(float2v a, float2v b, float2v c) {
  float2v d;
  asm("v_pk_fma_f32 %0, %1, %2, %3" : "=v"(d) : "v"(a), "v"(b), "v"(c));
  return d;
}
__device__ inline float2v pk_add(float2v a, float2v b) {
  float2v d;
  asm("v_pk_add_f32 %0, %1, %2" : "=v"(d) : "v"(a), "v"(b));
  return d;
}

// Serial stable top-16 insert for one 64-candidate group (unchanged from v5).
__device__ inline void insert_group(float d, int base, float t, int lane,
                                    float& sd, int& sj, float& s15) {
  unsigned long long m = __ballot(d <= t);
  while (m) {                          // m is wave-uniform
    const int src = __ffsll(m) - 1;    // ascending lane == ascending j
    m &= m - 1;
    const float dc = __shfl(d, src);
    if (dc < s15) {                    // recheck vs running bound
      const int jc = base + src;
      const unsigned long long bm = __ballot(sd <= dc) & 0xFFFFull;
      const int pos = (int)__popcll(bm);      // stable position
      const float pu = __shfl_up(sd, 1);
      const int ju = __shfl_up(sj, 1);
      if (lane < 16) {
        if (lane > pos)        { sd = pu; sj = ju; }
        else if (lane == pos)  { sd = dc; sj = jc; }
      }
      s15 = __shfl(sd, 15);
    }
  }
}

// ---------------------------------------------------------------------------
// MERGED prologue kernel (R9): knn_prep + convert_w(layer a) + convert_w
// (layer b) in one 1024-block launch. All three are mutually independent and
// feed later kernels only -> 8 dispatches become 6, and the convert_b bubble
// between edge_a and gemm_b disappears. Math byte-identical to the frozen
// knn_prep/convert_w kernels.
// ---------------------------------------------------------------------------
__global__ __launch_bounds__(256) void prep_convert_kernel(
    const float* __restrict__ xyz, float4* __restrict__ xyz4,
    const float* __restrict__ W1a, short* __restrict__ bhiA,
    short* __restrict__ bloA, const float* __restrict__ W1b,
    short* __restrict__ bhiB, short* __restrict__ bloB) {
  const int b = blockIdx.x;      // 0..1023
  const int k = threadIdx.x;     // 0..255

  if (b < 32) {                  // xyz4 prep (exact knn_prep rounding)
    const int i = b * 256 + k;
    float x = xyz[3 * i], y = xyz[3 * i + 1], z = xyz[3 * i + 2];
    float sq = __fadd_rn(__fadd_rn(__fmul_rn(x, x), __fmul_rn(y, y)),
                         __fmul_rn(z, z));
    xyz4[i] = make_float4(x, y, z, sq);
  }

  const int n = b & 511;         // 0..511
  const float* W1 = (b < 512) ? W1a : W1b;
  short* bhi = (b < 512) ? bhiA : bhiB;
  short* blo = (b < 512) ? bloA : bloB;
  const float v = (n < 256) ? W1[k * DTOK + n]
                            : W1[(259 + k) * DTOK + (n - 256)];
  short h = f2bf(v);
  bhi[n * 256 + k] = h;
  blo[n * 256 + k] = f2bf(v - bf2f(h));
}

// ---------------------------------------------------------------------------
// KNN v11 (R7 verbatim, best verified): 2 queries/wave, LDS-staged pass A +
// GLOBAL-STREAMED pass B (VMEM pipe, no barriers). R8's horizontal fusion
// with gemm_a gave ZERO overlap (71us fused ~= 40+30 serial) and a tail --
// reverted. Distances bit-identical to reference; nbr bit-identical.
// ---------------------------------------------------------------------------
#define KCH 512                     // candidates per staged chunk (pass A)
#define NCH (N_PTS / KCH)           // 16 chunks

__global__ __launch_bounds__(256) void knn_select_kernel(
    const float4* __restrict__ xyz4, int* __restrict__ nbr) {
  __shared__ float4 sA[2][4][64];   // {x0,x1,y0,y1} per pair, 8 KB
  __shared__ float4 sB[2][4][64];   // {z0,z1,w0,w1} per pair, 8 KB
  const int tid = threadIdx.x;
  const int lane = tid & 63;
  const int wave = tid >> 6;
  const int i0 = blockIdx.x * 8 + wave * 2;
  const int i1 = i0 + 1;

  const float4 q0 = xyz4[i0];
  const float4 q1 = xyz4[i1];
  const float2v x02 = {q0.x, q0.x}, y02 = {q0.y, q0.y};
  const float2v z02 = {q0.z, q0.z}, s02 = {q0.w, q0.w};
  const float2v x12 = {q1.x, q1.x}, y12 = {q1.y, q1.y};
  const float2v z12 = {q1.z, q1.z}, s12 = {q1.w, q1.w};
  const float2v n2 = {-2.0f, -2.0f};

  const int ib128 = i0 & ~127;      // uniform: shared 128-block of i0,i1
  const int ih0 = (i0 >> 6) & 1, il0 = i0 & 63;   // uniform
  const int ih1 = (i1 >> 6) & 1, il1 = i1 & 63;   // uniform

  // staging coords: wave w stages pair-group ps=w of each chunk
  const int sgj = wave * 128 + lane;

  // ---- prologue: stage chunk 0 ----
  {
    const float4 c0 = xyz4[sgj];
    const float4 c1 = xyz4[sgj + 64];
    sA[0][wave][lane] = make_float4(c0.x, c1.x, c0.y, c1.y);
    sB[0][wave][lane] = make_float4(c0.z, c1.z, c0.w, c1.w);
  }
  __syncthreads();

  // ---- pass A: per-lane running mins (both queries) over staged chunks ----
  float a00 = FLT_MAX, a01 = FLT_MAX, a10 = FLT_MAX, a11 = FLT_MAX;
  for (int c = 0; c < NCH; ++c) {
    const int b = c & 1;
    float4 nx0, nx1;
    if (c < NCH - 1) {              // issue next-chunk loads early (T14)
      nx0 = xyz4[(c + 1) * KCH + sgj];
      nx1 = xyz4[(c + 1) * KCH + sgj + 64];
    }
    const int cbase = c * KCH;
    #pragma unroll
    for (int ps = 0; ps < 4; ++ps) {
      const float4 a = sA[b][ps][lane];
      const float4 bb = sB[b][ps][lane];
      const float2v px = {a.x, a.y}, py = {a.z, a.w};
      const float2v pz = {bb.x, bb.y}, pw = {bb.z, bb.w};
      const bool selfg = (cbase + ps * 128 == ib128);   // uniform
      const float2v dot0 =
          pk_fma(z02, pz, pk_fma(y02, py, pk_mul(x02, px)));
      float2v d0 = pk_add(pk_fma(n2, dot0, s02), pw);
      const float2v dot1 =
          pk_fma(z12, pz, pk_fma(y12, py, pk_mul(x12, px)));
      float2v d1 = pk_add(pk_fma(n2, dot1, s12), pw);
      if (selfg) {                        // uniform rare branch
        if (lane == il0) {
          if (ih0) d0.y = __fadd_rn(d0.y, 1e10f);
          else     d0.x = __fadd_rn(d0.x, 1e10f);
        }
        if (lane == il1) {
          if (ih1) d1.y = __fadd_rn(d1.y, 1e10f);
          else     d1.x = __fadd_rn(d1.x, 1e10f);
        }
      }
      a00 = fminf(a00, d0.x);
      a01 = fminf(a01, d0.y);
      a10 = fminf(a10, d1.x);
      a11 = fminf(a11, d1.y);
    }
    if (c < NCH - 1) {              // LDS write late; latency hidden
      sA[b ^ 1][wave][lane] = make_float4(nx0.x, nx1.x, nx0.y, nx1.y);
      sB[b ^ 1][wave][lane] = make_float4(nx0.z, nx1.z, nx0.w, nx1.w);
    }
    __syncthreads();
  }

  // ---- two interleaved 64-lane bitonic sorts (ascending) of lane-mins ----
  float v0 = fminf(a00, a01);
  float v1 = fminf(a10, a11);
  #pragma unroll
  for (int k = 2; k <= 64; k <<= 1) {
    #pragma unroll
    for (int j = k >> 1; j > 0; j >>= 1) {
      const float o0 = __shfl_xor(v0, j, 64);
      const float o1 = __shfl_xor(v1, j, 64);
      const bool keepmin = ((lane & k) == 0) == ((lane & j) == 0);
      v0 = keepmin ? fminf(v0, o0) : fmaxf(v0, o0);
      v1 = keepmin ? fminf(v1, o1) : fmaxf(v1, o1);
    }
  }
  const float t0 = __shfl(v0, 15, 64);  // >= true 16th-smallest dist (q0)
  const float t1 = __shfl(v1, 15, 64);  // >= true 16th-smallest dist (q1)

  // ---- pass B: stream DIRECTLY from global (L2-resident), no barriers ----
  float sd0 = FLT_MAX, sd1 = FLT_MAX;   // slot dists (lanes 0..15)
  int sj0 = 0, sj1 = 0;                 // slot indices
  float s150 = FLT_MAX, s151 = FLT_MAX; // running 16th-best (uniform)

  const int gself = i0 >> 6;            // uniform: 64-group holding i0,i1

  float4 pc = xyz4[lane];               // group 0 prefetch
  #pragma unroll 2
  for (int grp = 0; grp < N_PTS / 64; ++grp) {
    float4 pn;
    if (grp < N_PTS / 64 - 1) pn = xyz4[(grp + 1) * 64 + lane];

    // scalar distance chain == pk chain op-for-op (bit-identical)
    const float dot0 = fmaf(q0.z, pc.z, fmaf(q0.y, pc.y,
                                             __fmul_rn(q0.x, pc.x)));
    float d0 = __fadd_rn(__fmaf_rn(-2.0f, dot0, q0.w), pc.w);
    const float dot1 = fmaf(q1.z, pc.z, fmaf(q1.y, pc.y,
                                             __fmul_rn(q1.x, pc.x)));
    float d1 = __fadd_rn(__fmaf_rn(-2.0f, dot1, q1.w), pc.w);
    if (grp == gself) {                 // uniform rare branch
      if (lane == il0) d0 = __fadd_rn(d0, 1e10f);
      if (lane == il1) d1 = __fadd_rn(d1, 1e10f);
    }

    insert_group(d0, grp * 64, t0, lane, sd0, sj0, s150);
    insert_group(d1, grp * 64, t1, lane, sd1, sj1, s151);
    pc = pn;
  }

  if (lane < 16) {
    nbr[i0 * KNN + lane] = sj0;
    nbr[i1 * KNN + lane] = sj1;
  }
}

// ---------------------------------------------------------------------------
// pq GEMM v2 (frozen from R9 of the previous session).
// ---------------------------------------------------------------------------
__global__ __launch_bounds__(256, 2) void pq_gemm_fused_kernel(
    const float* __restrict__ A, const short* __restrict__ Bthi,
    const short* __restrict__ Btlo, const float* __restrict__ xyz,
    const float* __restrict__ W1, const float* __restrict__ b1,
    float* __restrict__ R, float* __restrict__ Q) {
  __shared__ short Ahi[64][32], Alo[64][32];    // 4K + 4K
  __shared__ short Bhi[128][32], Blo[128][32];  // 8K + 8K
  __shared__ float Qs[64][65];                  // 16.6K
  __shared__ float sx[64][3];
  __shared__ float swz[6][64];
  __shared__ float sb1[64];

  const int tid = threadIdx.x;
  const int lane = tid & 63;
  const int wave = tid >> 6;
  const int l15 = lane & 15;
  const int quad = lane >> 4;
  const int mh = wave & 1;
  const int qh = wave >> 1;
  const int m0 = blockIdx.x * 64;
  const int np0 = blockIdx.y * 64;

  if (tid < 64) {
    sx[tid][0] = xyz[(m0 + tid) * 3];
    sx[tid][1] = xyz[(m0 + tid) * 3 + 1];
    sx[tid][2] = xyz[(m0 + tid) * 3 + 2];
  } else if (tid < 128) {
    int n = tid - 64;
    sb1[n] = b1[np0 + n];
    #pragma unroll
    for (int r = 0; r < 3; ++r) {
      swz[r][n] = W1[(256 + r) * DTOK + np0 + n];
      swz[3 + r][n] = W1[(515 + r) * DTOK + np0 + n];
    }
  }

  float4v acc[2][4];
  #pragma unroll
  for (int mf = 0; mf < 2; ++mf)
    #pragma unroll
    for (int nf = 0; nf < 4; ++nf)
      #pragma unroll
      for (int e = 0; e < 4; ++e) acc[mf][nf][e] = 0.f;

  const int ar = tid >> 2;             // A staging row 0..63
  const int ak = (tid & 3) * 8;        // A staging k-offset

  #pragma unroll 1
  for (int kc = 0; kc < 8; ++kc) {
    const int k0 = kc * 32;
    __syncthreads();
    {
      const float* asrc = A + (size_t)(m0 + ar) * 256 + k0 + ak;
      float4 a0 = *(const float4*)asrc;
      float4 a1 = *(const float4*)(asrc + 4);
      float v[8] = {a0.x, a0.y, a0.z, a0.w, a1.x, a1.y, a1.z, a1.w};
      short8 h8, l8;
      #pragma unroll
      for (int e = 0; e < 8; ++e) {
        short h = f2bf(v[e]);
        h8[e] = h;
        l8[e] = f2bf(v[e] - bf2f(h));
      }
      *(short8*)(&Ahi[ar][ak]) = h8;
      *(short8*)(&Alo[ar][ak]) = l8;
    }
    #pragma unroll
    for (int l = 0; l < 4; ++l) {
      const int rem = tid + 256 * (l & 1);
      const int row = rem >> 2;
      const int koff = (rem & 3) * 8;
      const int n = (row < 64) ? (np0 + row) : (256 + np0 + row - 64);
      const short* src = ((l < 2) ? Bthi : Btlo) + (size_t)n * 256 + k0 + koff;
      short8 vv = *(const short8*)src;
      if (l < 2) *(short8*)(&Bhi[row][koff]) = vv;
      else       *(short8*)(&Blo[row][koff]) = vv;
    }
    __syncthreads();

    short8 ah[2], al[2], bh[4], bl[4];
    #pragma unroll
    for (int mf = 0; mf < 2; ++mf) {
      ah[mf] = *(const short8*)(&Ahi[mh * 32 + mf * 16 + l15][quad * 8]);
      al[mf] = *(const short8*)(&Alo[mh * 32 + mf * 16 + l15][quad * 8]);
    }
    #pragma unroll
    for (int nf = 0; nf < 4; ++nf) {
      bh[nf] = *(const short8*)(&Bhi[qh * 64 + nf * 16 + l15][quad * 8]);
      bl[nf] = *(const short8*)(&Blo[qh * 64 + nf * 16 + l15][quad * 8]);
    }
    #pragma unroll
    for (int mf = 0; mf < 2; ++mf)
      #pragma unroll
      for (int nf = 0; nf < 4; ++nf) {
        acc[mf][nf] = __builtin_amdgcn_mfma_f32_16x16x32_bf16(
            ah[mf], bh[nf], acc[mf][nf], 0, 0, 0);
        acc[mf][nf] = __builtin_amdgcn_mfma_f32_16x16x32_bf16(
            ah[mf], bl[nf], acc[mf][nf], 0, 0, 0);
        acc[mf][nf] = __builtin_amdgcn_mfma_f32_16x16x32_bf16(
            al[mf], bh[nf], acc[mf][nf], 0, 0, 0);
      }
  }

  if (qh == 1) {
    #pragma unroll
    for (int mf = 0; mf < 2; ++mf)
      #pragma unroll
      for (int nf = 0; nf < 4; ++nf)
        #pragma unroll
        for (int e = 0; e < 4; ++e) {
          int row = mh * 32 + mf * 16 + quad * 4 + e;
          int col = nf * 16 + l15;
          float q = acc[mf][nf][e] + sx[row][0] * swz[3][col] +
                    sx[row][1] * swz[4][col] + sx[row][2] * swz[5][col];
          Qs[row][col] = q;
          Q[(size_t)(m0 + row) * DTOK + np0 + col] = q;
        }
  }
  __syncthreads();
  if (qh == 0) {
    #pragma unroll
    for (int mf = 0; mf < 2; ++mf)
      #pragma unroll
      for (int nf = 0; nf < 4; ++nf)
        #pragma unroll
        for (int e = 0; e < 4; ++e) {
          int row = mh * 32 + mf * 16 + quad * 4 + e;
          int col = nf * 16 + l15;
          float p = acc[mf][nf][e] + sx[row][0] * swz[0][col] +
                    sx[row][1] * swz[1][col] + sx[row][2] * swz[2][col];
          R[(size_t)(m0 + row) * DTOK + np0 + col] =
              (p + sb1[col]) - Qs[row][col];
        }
  }
}

// ---------------------------------------------------------------------------
// EdgeConv via MFMA (EXACT R10 version -- R11's global-B variant regressed
// 68 -> ~110 us/launch; W2 register fragments restored).
// ---------------------------------------------------------------------------
#define EP 8          // points per group

__global__ __launch_bounds__(256, 2) void edge_mfma_kernel(
    const float* __restrict__ R, const float* __restrict__ Q,
    const int* __restrict__ nbr, const float* __restrict__ W2,
    const float* __restrict__ b2, float* __restrict__ out,
    int num_groups, int groups_per_block) {
  __shared__ short Hs[EP * KNN * DTOK];   // 128 rows x 256, 64 KB
  const int lane = threadIdx.x & 63;
  const int wave = threadIdx.x >> 6;
  const int l15 = lane & 15;
  const int quad = lane >> 4;

  short8 bfr[4][8];
  #pragma unroll
  for (int nt_i = 0; nt_i < 4; ++nt_i) {
    const int n = (wave * 4 + nt_i) * 16 + l15;
    #pragma unroll
    for (int kt = 0; kt < 8; ++kt) {
      short8 f;
      #pragma unroll
      for (int jj = 0; jj < 8; ++jj) {
        int k = kt * 32 + quad * 8 + jj;
        f[jj] = f2bf(W2[k * DTOK + n]);
      }
      bfr[nt_i][kt] = f;
    }
  }

  const int wc8 = lane >> 1;
  const int wsub = (lane & 1) * 4;

  for (int gi = 0; gi < groups_per_block; ++gi) {
    const int g = blockIdx.x + gi * gridDim.x;
    if (g >= num_groups) break;
    const int i0 = g * EP;

    // ---- build H: prefetched nbr via lane reg + shfl, pipelined gathers ----
    {
      const int ia = i0 + wave * 2;
      const int jr0 = nbr[ia * KNN + l15];
      const int jr1 = nbr[(ia + 1) * KNN + l15];
      const float4 ri0 = ((const float4*)(R + (size_t)ia * DTOK))[lane];
      const float4 ri1 = ((const float4*)(R + (size_t)(ia + 1) * DTOK))[lane];
      #pragma unroll
      for (int pp = 0; pp < 2; ++pp) {
        const float4 ri = pp ? ri1 : ri0;
        const int jr = pp ? jr1 : jr0;
        #pragma unroll
        for (int k = 0; k < KNN; ++k) {
          const int j = __shfl(jr, k, 16);
          const float4 qj = ((const float4*)(Q + (size_t)j * DTOK))[lane];
          const int r = wave * 32 + pp * 16 + k;
          uint2 pk;
          pk.x = ((unsigned)(unsigned short)f2bf(fmaxf(ri.x + qj.x, 0.f))) |
                 (((unsigned)(unsigned short)f2bf(fmaxf(ri.y + qj.y, 0.f))) << 16);
          pk.y = ((unsigned)(unsigned short)f2bf(fmaxf(ri.z + qj.z, 0.f))) |
                 (((unsigned)(unsigned short)f2bf(fmaxf(ri.w + qj.w, 0.f))) << 16);
          *(uint2*)(&Hs[r * DTOK + ((wc8 ^ (r & 7)) << 3) + wsub]) = pk;
        }
      }
    }
    __syncthreads();

    #pragma unroll
    for (int mp = 0; mp < 4; ++mp) {
      float4v acc[2][4];
      #pragma unroll
      for (int mi = 0; mi < 2; ++mi)
        #pragma unroll
        for (int nt_i = 0; nt_i < 4; ++nt_i)
          #pragma unroll
          for (int e = 0; e < 4; ++e) acc[mi][nt_i][e] = 0.f;

      #pragma unroll
      for (int kt = 0; kt < 8; ++kt) {
        const int pc = ((kt * 4 + quad) ^ (l15 & 7)) << 3;
        const short8 a0 = *(const short8*)(
            &Hs[((mp * 2 + 0) * 16 + l15) * DTOK + pc]);
        const short8 a1 = *(const short8*)(
            &Hs[((mp * 2 + 1) * 16 + l15) * DTOK + pc]);
        #pragma unroll
        for (int nt_i = 0; nt_i < 4; ++nt_i) {
          acc[0][nt_i] = __builtin_amdgcn_mfma_f32_16x16x32_bf16(
              a0, bfr[nt_i][kt], acc[0][nt_i], 0, 0, 0);
          acc[1][nt_i] = __builtin_amdgcn_mfma_f32_16x16x32_bf16(
              a1, bfr[nt_i][kt], acc[1][nt_i], 0, 0, 0);
        }
      }

      #pragma unroll
      for (int mi = 0; mi < 2; ++mi) {
        #pragma unroll
        for (int nt_i = 0; nt_i < 4; ++nt_i) {
          float rm = fmaxf(fmaxf(acc[mi][nt_i][0], acc[mi][nt_i][1]),
                           fmaxf(acc[mi][nt_i][2], acc[mi][nt_i][3]));
          rm = fmaxf(rm, __shfl_xor(rm, 16, 64));
          rm = fmaxf(rm, __shfl_xor(rm, 32, 64));
          if (lane < 16) {
            const int i = i0 + mp * 2 + mi;
            const int n = (wave * 4 + nt_i) * 16 + lane;
            out[(size_t)i * DTOK + n] = rm + b2[n];
          }
        }
      }
    }
    __syncthreads();
  }
}

// ---------------------------------------------------------------------------
extern "C" void kernel_launch(void* const* d_in, const int* in_sizes, int n_in,
                              void* d_out, int out_size, void* d_ws,
                              size_t ws_size, hipStream_t stream) {
  const float* xyz = (const float*)d_in[0];
  const float* feat = (const float*)d_in[1];
  const float* W1a = (const float*)d_in[2];
  const float* b1a = (const float*)d_in[3];
  const float* W2a = (const float*)d_in[4];
  const float* b2a = (const float*)d_in[5];
  const float* W1b = (const float*)d_in[6];
  const float* b1b = (const float*)d_in[7];
  const float* W2b = (const float*)d_in[8];
  const float* b2b = (const float*)d_in[9];
  float* out = (float*)d_out;

  // ws layout (~25 MB): nbr 0.5 | xyz4 128KB | Bt_b @w1+1MB (512KB, in the
  // free w1+[128KB,8MB) gap) | R @w1+8MB | Q @w1+16MB | Bt_a @w1+24MB
  char* w = (char*)d_ws;
  const size_t SZ_NBR = (size_t)N_PTS * KNN * sizeof(int);        // 512 KB
  const size_t MB = 1024 * 1024;
  int* nbr = (int*)w;
  char* w1 = w + SZ_NBR;
  float4* xyz4 = (float4*)w1;                  // 128 KB
  short* BthiB = (short*)(w1 + 1 * MB);        // 256 KB (free region)
  short* BtloB = BthiB + 512 * 256;            // 256 KB
  float* R = (float*)(w1 + 8 * MB);            // 8 MB
  float* Q = (float*)(w1 + 16 * MB);           // 8 MB
  short* BthiA = (short*)(w1 + 24 * MB);       // 256 KB
  short* BtloA = BthiA + 512 * 256;            // 256 KB
  float* bufC = out;                           // layer-a output staging

  const int num_groups = N_PTS / EP;           // 1024
  const int nblocks = 512;

  // merged prologue: xyz4 prep + both weight conversions (one dispatch)
  prep_convert_kernel<<<1024, 256, 0, stream>>>(
      xyz, xyz4, W1a, BthiA, BtloA, W1b, BthiB, BtloB);

  knn_select_kernel<<<N_PTS / 8, 256, 0, stream>>>(xyz4, nbr);

  // layer a
  pq_gemm_fused_kernel<<<dim3(N_PTS / 64, 4), 256, 0, stream>>>(
      feat, BthiA, BtloA, xyz, W1a, b1a, R, Q);
  edge_mfma_kernel<<<nblocks, 256, 0, stream>>>(R, Q, nbr, W2a, b2a, bufC,
                                                num_groups, 2);

  // layer b
  pq_gemm_fused_kernel<<<dim3(N_PTS / 64, 4), 256, 0, stream>>>(
      bufC, BthiB, BtloB, xyz, W1b, b1b, R, Q);
  edge_mfma_kernel<<<nblocks, 256, 0, stream>>>(R, Q, nbr, W2b, b2b, out,
                                                num_groups, 2);
}